// Round 7
// baseline (560.305 us; speedup 1.0000x reference)
//
#include <hip/hip_runtime.h>
#include <stdint.h>

typedef unsigned short u16;
typedef __attribute__((ext_vector_type(8))) short bf16x8;      // 8 bf16 = 4 VGPRs
typedef __attribute__((ext_vector_type(8))) unsigned short u16x8;
typedef __attribute__((ext_vector_type(4))) float f32x4;

#define B_  2
#define T_  4096
#define C_  2048
#define NH  16
#define NKV 4
#define HD  128

__device__ __forceinline__ u16 f2bf(float f) {
  union { float f; uint32_t u; } v; v.f = f;
  uint32_t u = v.u;
  u += 0x7fffu + ((u >> 16) & 1u);   // RNE
  return (u16)(u >> 16);
}
__device__ __forceinline__ float bf2f(u16 h) {
  union { uint32_t u; float f; } v; v.u = ((uint32_t)h) << 16;
  return v.f;
}

__device__ __forceinline__ void gload_lds16(const u16* g, u16* l) {
  __builtin_amdgcn_global_load_lds(
      (const __attribute__((address_space(1))) void*)g,
      (__attribute__((address_space(3))) void*)l, 16, 0, 0);
}

// ---------------- fused f32 -> bf16 convert (x, wq, wk, wv, wo in one grid) ----------------
__global__ void cvt_all(const float* __restrict__ x, const float* __restrict__ wq,
                        const float* __restrict__ wk, const float* __restrict__ wv,
                        const float* __restrict__ wo, u16* __restrict__ xb,
                        u16* __restrict__ wqkv, u16* __restrict__ wob) {
  long i = ((long)blockIdx.x * 256 + threadIdx.x) * 4;
  const float* src; u16* dst; long off;
  if (i < 16777216L)      { src = x;  dst = xb;              off = i; }
  else if (i < 20971520L) { src = wq; dst = wqkv;            off = i - 16777216L; }
  else if (i < 22020096L) { src = wk; dst = wqkv + 4194304L; off = i - 20971520L; }
  else if (i < 23068672L) { src = wv; dst = wqkv + 5242880L; off = i - 22020096L; }
  else                    { src = wo; dst = wob;             off = i - 23068672L; }
  float4 v = *(const float4*)(src + off);
  ushort4 o4;
  o4.x = f2bf(v.x); o4.y = f2bf(v.y); o4.z = f2bf(v.z); o4.w = f2bf(v.w);
  *(ushort4*)(dst + off) = o4;
}

// ---------------- K rearrange: frag-linear layout ----------------
// K2[bk][kb=key/16][ks=d/32][q4][l16=key%16][e=d%8]
__global__ void krearr(const u16* __restrict__ qkv, u16* __restrict__ K2) {
  int gid = blockIdx.x * 256 + threadIdx.x;
  int r = gid & 65535, bk = gid >> 16;
  int l16 = r & 15, q4 = (r >> 4) & 3, ks = (r >> 6) & 3, kb = r >> 8;
  int bb = bk >> 2, kv = bk & 3;
  const u16* src = qkv + ((long)(bb * T_ + kb * 16 + l16)) * 3072 + 2048 + kv * HD +
                   ks * 32 + q4 * 8;
  *(u16x8*)(K2 + (long)bk * 524288 + (long)r * 8) = *(const u16x8*)src;
}

// ---------------- V rearrange via LDS transpose (coalesced both sides) ----------------
// V2[bk][kc=key/128][jd=d/16][ks=(key%128)/32][q4][l16=d%16][e=key%8]
__global__ __launch_bounds__(256) void vrearr2(const u16* __restrict__ qkv,
                                               u16* __restrict__ V2) {
  const int bid = blockIdx.x;          // 0..255
  const int bk = bid >> 5, kc = bid & 31;
  const int bb = bk >> 2, kv = bk & 3;
  const int t = threadIdx.x;
  __shared__ u16 L[128 * 136];         // [key][d], pad 8 u16 (16B-aligned rows)
  {
    int key = t >> 1;
    int dh = (t & 1) * 64;
    const u16* src = qkv + ((long)(bb * T_ + kc * 128 + key)) * 3072 + 2560 + kv * HD + dh;
    u16* dst = L + key * 136 + dh;
#pragma unroll
    for (int u = 0; u < 8; u++)
      *(u16x8*)(dst + u * 8) = *(const u16x8*)(src + u * 8);
  }
  __syncthreads();
  u16* out = V2 + (long)bk * 524288 + (long)kc * 16384;
#pragma unroll
  for (int step = 0; step < 8; step++) {
    int o = step * 256 + t;            // 0..2047
    int l16 = o & 15, q4 = (o >> 4) & 3, ks = (o >> 6) & 3, jd = (o >> 8) & 7;
    int keyb = ks * 32 + q4 * 8;
    int d = jd * 16 + l16;
    u16x8 v;
#pragma unroll
    for (int e = 0; e < 8; e++) v[e] = L[(keyb + e) * 136 + d];
    *(u16x8*)(out + (long)o * 8) = v;
  }
}

// ---------------- bf16 GEMM: C[M][N] = A[M][K] * B[N][K]^T ----------------
// 256x256 tile, BK=64, 8 waves (2M x 4N), double-buffered 128 KiB LDS.
// READ-AHEAD pipeline, 2 barriers per K-tile (R2 structure, proven 121.6 us).
// Fused RoPE epilogue via LDS rope table.
#define GBAR() __builtin_amdgcn_s_barrier()
#define LGKM0() do { asm volatile("s_waitcnt lgkmcnt(0)" ::: "memory"); \
                     __builtin_amdgcn_sched_barrier(0); } while (0)

template <int WRITE_BF16, int ROPE>
__global__ __launch_bounds__(512, 2) void gemm256(const u16* __restrict__ A,
                                                  const u16* __restrict__ Bw,
                                                  void* __restrict__ Cv,
                                                  const float* __restrict__ rope,
                                                  int M, int N, int K) {
  __shared__ __align__(16) u16 lds[65536];   // 128 KiB
  const int tid = threadIdx.x;
  const int lane = tid & 63;
  const int wave = tid >> 6;
  const int q4 = lane >> 4, l16 = lane & 15;
  const int wm = wave >> 2, wn = wave & 3;

  // bijective XCD swizzle (launcher guarantees nwg % 8 == 0)
  const int nwg = gridDim.x * gridDim.y;
  const int orig = blockIdx.y * gridDim.x + blockIdx.x;
  const int swz = (orig & 7) * (nwg >> 3) + (orig >> 3);
  const int bm = swz / gridDim.x, bn = swz % gridDim.x;
  const long m0 = (long)bm * 256, n0 = (long)bn * 256;

  // ---- staging addressing: thread t -> LDS linear t*16 bytes (+8192) ----
  const int srow = tid >> 2;            // 0..127  (second load: +128)
  const int slot = tid & 3;
  const int sx = (slot ^ ((srow >> 1) & 3)) * 8;   // (srow+128) gives same XOR
  const u16* Ag0 = A + (m0 + srow) * K + sx;
  const u16* Ag1 = A + (m0 + srow + 128) * K + sx;
  const u16* Bg0 = Bw + (n0 + srow) * K + sx;
  const u16* Bg1 = Bw + (n0 + srow + 128) * K + sx;
  u16* ldst = lds + tid * 8;            // u16 units

  const int nkt = K >> 6;

#define STAGE_A(bufi, kh, kt)                                  \
  do {                                                         \
    long ko = ((long)(kt) << 6) + ((kh) << 5);                 \
    u16* d = ldst + (bufi) * 32768 + (kh) * 8192;              \
    gload_lds16(Ag0 + ko, d);                                  \
    gload_lds16(Ag1 + ko, d + 4096);                           \
  } while (0)
#define STAGE_B(bufi, kh, kt)                                  \
  do {                                                         \
    long ko = ((long)(kt) << 6) + ((kh) << 5);                 \
    u16* d = ldst + (bufi) * 32768 + 16384 + (kh) * 8192;      \
    gload_lds16(Bg0 + ko, d);                                  \
    gload_lds16(Bg1 + ko, d + 4096);                           \
  } while (0)

  // fragment LDS offsets (u16 units) for kh=0; kh=1 adds 8192.
  int offA[8], offB[4];
#pragma unroll
  for (int m = 0; m < 8; m++) {
    int r = wm * 128 + m * 16 + l16;
    offA[m] = r * 32 + ((q4 ^ ((r >> 1) & 3)) << 3);
  }
#pragma unroll
  for (int n = 0; n < 4; n++) {
    int r = wn * 64 + n * 16 + l16;
    offB[n] = 16384 + r * 32 + ((q4 ^ ((r >> 1) & 3)) << 3);
  }

  f32x4 acc[8][4] = {};

  // ---- prologue: tile0 (4 half-stages) + tile1 k0 (2 half-stages) ----
  STAGE_A(0, 0, 0); STAGE_B(0, 0, 0); STAGE_A(0, 1, 0); STAGE_B(0, 1, 0);
  if (nkt > 1) {
    STAGE_A(1, 0, 1); STAGE_B(1, 0, 1);
    asm volatile("s_waitcnt vmcnt(4)" ::: "memory");
  } else {
    asm volatile("s_waitcnt vmcnt(0)" ::: "memory");
  }
  GBAR();

  bf16x8 afX[4], afY[4], bvA[4], bvB[4];
  for (int kt = 0; kt < nkt; kt++) {
    const int bo = (kt & 1) * 32768;    // current read buffer offset (u16)
    // ---- P1: R1 (cold) ; stage A-k1 ; wait ; R2 under MFMA ----
#pragma unroll
    for (int m = 0; m < 4; m++) afX[m] = *(const bf16x8*)(lds + bo + offA[m]);
#pragma unroll
    for (int n = 0; n < 4; n++) bvA[n] = *(const bf16x8*)(lds + bo + offB[n]);
    if (kt + 1 < nkt) STAGE_A((kt + 1) & 1, 1, kt + 1);
    LGKM0();
#pragma unroll
    for (int m = 0; m < 4; m++) afY[m] = *(const bf16x8*)(lds + bo + offA[4 + m]);
    __builtin_amdgcn_s_setprio(1);
#pragma unroll
    for (int m = 0; m < 4; m++)
#pragma unroll
      for (int n = 0; n < 4; n++)
        acc[m][n] = __builtin_amdgcn_mfma_f32_16x16x32_bf16(afX[m], bvA[n], acc[m][n], 0, 0, 0);
    __builtin_amdgcn_s_setprio(0);
    // ---- P2: stage B-k1 ; wait R2 ; R3 under MFMA ; mid-BAR ----
    if (kt + 1 < nkt) STAGE_B((kt + 1) & 1, 1, kt + 1);
    LGKM0();
#pragma unroll
    for (int m = 0; m < 4; m++) afX[m] = *(const bf16x8*)(lds + bo + 8192 + offA[m]);
#pragma unroll
    for (int n = 0; n < 4; n++) bvB[n] = *(const bf16x8*)(lds + bo + 8192 + offB[n]);
    __builtin_amdgcn_s_setprio(1);
#pragma unroll
    for (int m = 0; m < 4; m++)
#pragma unroll
      for (int n = 0; n < 4; n++)
        acc[4 + m][n] = __builtin_amdgcn_mfma_f32_16x16x32_bf16(afY[m], bvA[n], acc[4 + m][n], 0, 0, 0);
    __builtin_amdgcn_s_setprio(0);
    GBAR();                              // k0 globally consumed -> reusable
    // ---- P3: stage A-k0(kt+2) into cur ; wait R3 ; R4 under MFMA ----
    if (kt + 2 < nkt) STAGE_A(kt & 1, 0, kt + 2);
    LGKM0();
#pragma unroll
    for (int m = 0; m < 4; m++) afY[m] = *(const bf16x8*)(lds + bo + 8192 + offA[4 + m]);
    __builtin_amdgcn_s_setprio(1);
#pragma unroll
    for (int m = 0; m < 4; m++)
#pragma unroll
      for (int n = 0; n < 4; n++)
        acc[m][n] = __builtin_amdgcn_mfma_f32_16x16x32_bf16(afX[m], bvB[n], acc[m][n], 0, 0, 0);
    __builtin_amdgcn_s_setprio(0);
    // ---- P4: stage B-k0(kt+2) ; wait R4 ; MFMA ; counted vmcnt ; BAR ----
    if (kt + 2 < nkt) STAGE_B(kt & 1, 0, kt + 2);
    LGKM0();
    __builtin_amdgcn_s_setprio(1);
#pragma unroll
    for (int m = 0; m < 4; m++)
#pragma unroll
      for (int n = 0; n < 4; n++)
        acc[4 + m][n] = __builtin_amdgcn_mfma_f32_16x16x32_bf16(afY[m], bvB[n], acc[4 + m][n], 0, 0, 0);
    __builtin_amdgcn_s_setprio(0);
    if (kt + 2 < nkt)
      asm volatile("s_waitcnt vmcnt(4)" ::: "memory");
    else
      asm volatile("s_waitcnt vmcnt(0)" ::: "memory");
    GBAR();
  }
#undef STAGE_A
#undef STAGE_B

  // ---- ROPE: stage this block's rope rows into (now dead) LDS ----
  if (ROPE) {
    float* rl = (float*)lds;
    const int rrow = tid >> 1;                 // 0..255
    const int rh = (tid & 1) * 64;             // col half
    const int rx = ((rrow >> 2) & 3) << 3;
    const float* rsrc = rope + ((long)((int)((m0 + rrow)) & (T_ - 1)) * 128 + rh);
    float* rdst = rl + rrow * 128;
#pragma unroll
    for (int v = 0; v < 16; v++) {
      int col = rh + v * 4;
      *(float4*)(rdst + (col ^ rx)) = *(const float4*)(rsrc + v * 4);
    }
    GBAR();
  }

  // ---- epilogue: C write, fused RoPE (C/D frag: row=q4*4+r, col=l16) ----
  const long crow0 = m0 + wm * 128;
  const long ccol0 = n0 + wn * 64;
  const float* rl = (const float*)lds;
#pragma unroll
  for (int m = 0; m < 8; m++)
#pragma unroll
    for (int n = 0; n < 4; n++) {
      const int cfrag = (int)(ccol0 + n * 16);
#pragma unroll
      for (int r = 0; r < 4; r++) {
        long row = crow0 + m * 16 + q4 * 4 + r;
        float x = acc[m][n][r];
        if (ROPE && cfrag < 2560) {
          int row_local = wm * 128 + m * 16 + q4 * 4 + r;      // (row_local>>2)&3 == q4
          int cc = ((cfrag & 127) + l16) ^ (q4 << 3);
          float2 cs = *(const float2*)(rl + row_local * 128 + (cc & ~1));  // (cos,sin)
          float px = __shfl_xor(x, 1, 64);
          // even (x=x0, px=x1): x0*cos - x1*sin ; odd (x=x1, px=x0): x0*sin + x1*cos
          float rot = ((l16 & 1) == 0) ? (x * cs.x - px * cs.y)
                                       : (px * cs.y + x * cs.x);
          if (cfrag < 2048) rot *= 0.1275174315f;  // q: 1/sqrt(D) * log2(e)
          x = rot;
        }
        if (WRITE_BF16)
          ((u16*)Cv)[row * (long)N + ccol0 + n * 16 + l16] = f2bf(x);
        else
          ((float*)Cv)[row * (long)N + ccol0 + n * 16 + l16] = x;
      }
    }
}

// ---------------- sliding-window attention ----------------
// R7 changes vs R6 (theory: latency-bound on depth-1 global K/V prefetch +
// no XCD L2 pinning):
//  1. XCD-chunked bijective swizzle: 1024 blocks / 8 XCDs = 128/XCD, which is
//     EXACTLY one (b,kvh) pair per XCD -> its 2 MB K2/V2 L2-resident.
//  2. V prefetch: 4-deep register ring (was 1-deep vn rotation).
//  3. K prefetch: 2-j-deep ring (8 loads in flight, was 4).
//  4. __launch_bounds__(256,4): 4 blocks/CU (LDS 136 KB) -> all 1024 blocks
//     resident in one generation, 4 waves/SIMD TLP.
__global__ __launch_bounds__(256, 4) void attn_kernel(const u16* __restrict__ qkv,
                                                      const u16* __restrict__ K2,
                                                      const u16* __restrict__ V2,
                                                      u16* __restrict__ y) {
  const int lin = blockIdx.x + (int)gridDim.x * (blockIdx.y + (int)gridDim.y * blockIdx.z);
  const int swz = (lin & 7) * 128 + (lin >> 3);   // bijective: 1024 = 8*128
  const int tc = swz & 31, h = (swz >> 5) & 15, b = swz >> 9;
  const int t0 = tc * 128;
  const int kvh = h >> 2;
  __shared__ u16 Pl[4 * 32 * 136];
  const int tid = threadIdx.x, wave = tid >> 6, lane = tid & 63;
  const int q4 = lane >> 4, l16 = lane & 15;
  u16* Pw = Pl + wave * (32 * 136);

  bf16x8 qf[2][4];
#pragma unroll
  for (int i = 0; i < 2; i++)
#pragma unroll
    for (int ks = 0; ks < 4; ks++)
      qf[i][ks] = *(const bf16x8*)(qkv +
          ((long)(b * T_ + t0 + 32 * wave + 16 * i + l16)) * 3072 + h * HD + ks * 32 + q4 * 8);

  f32x4 O[2][8] = {};
  float l_i[2][4] = {};

  const u16* Kb = K2 + (long)(b * NKV + kvh) * 524288 + lane * 8;
  const u16* Vb = V2 + (long)(b * NKV + kvh) * 524288 + lane * 8;

  int kstart = t0 - 256; if (kstart < 0) kstart = 0;
  for (int k0 = kstart; k0 <= t0; k0 += 128) {
    const u16* Kc = Kb + (long)(k0 >> 4) * 2048;     // kb0*4*512
    const u16* Vc = Vb + (long)(k0 >> 7) * 16384;    // kc*8*4*512
    const int dbase0 = t0 + 32 * wave + q4 * 4 - k0 - l16;
    // ---- S = Q K^T; K frags 2-j-deep ring; P -> wave-private LDS ----
    bf16x8 kr[2][4];
#pragma unroll
    for (int ks = 0; ks < 4; ks++) kr[0][ks] = *(const bf16x8*)(Kc + ks * 512);
#pragma unroll
    for (int ks = 0; ks < 4; ks++) kr[1][ks] = *(const bf16x8*)(Kc + 2048 + ks * 512);
#pragma unroll
    for (int j = 0; j < 8; j++) {
      bf16x8 kf[4];
#pragma unroll
      for (int ks = 0; ks < 4; ks++) kf[ks] = kr[j & 1][ks];
      if (j + 2 < 8)
#pragma unroll
        for (int ks = 0; ks < 4; ks++)
          kr[j & 1][ks] = *(const bf16x8*)(Kc + (j + 2) * 2048 + ks * 512);
      f32x4 s0 = {}, s1 = {};
#pragma unroll
      for (int ks = 0; ks < 4; ks++) {
        s0 = __builtin_amdgcn_mfma_f32_16x16x32_bf16(qf[0][ks], kf[ks], s0, 0, 0, 0);
        s1 = __builtin_amdgcn_mfma_f32_16x16x32_bf16(qf[1][ks], kf[ks], s1, 0, 0, 0);
      }
#pragma unroll
      for (int r = 0; r < 4; r++) {
        int d0 = dbase0 + r - 16 * j;               // q - k for i=0
        float p0 = __builtin_amdgcn_exp2f(s0[r]);
        p0 = ((unsigned)d0 <= 255u) ? p0 : 0.f;     // band mask, all chunks
        l_i[0][r] += p0;
        Pw[(q4 * 4 + r) * 136 + 16 * j + l16] = f2bf(p0);
        int d1 = d0 + 16;                            // i=1
        float p1 = __builtin_amdgcn_exp2f(s1[r]);
        p1 = ((unsigned)d1 <= 255u) ? p1 : 0.f;
        l_i[1][r] += p1;
        Pw[(16 + q4 * 4 + r) * 136 + 16 * j + l16] = f2bf(p1);
      }
    }
    // ---- O += P V ; V frags 4-deep register ring ----
    // step s = ks*8+jd consumes frag (jd*4+ks); preload s=0..3 (ks=0, jd=p -> frag 4p)
    bf16x8 vr[4];
#pragma unroll
    for (int p = 0; p < 4; p++)
      vr[p] = *(const bf16x8*)(Vc + (p * 4) * 512);
#pragma unroll
    for (int ks = 0; ks < 4; ks++) {
      bf16x8 pf0 = *(const bf16x8*)(&Pw[l16 * 136 + ks * 32 + q4 * 8]);
      bf16x8 pf1 = *(const bf16x8*)(&Pw[(16 + l16) * 136 + ks * 32 + q4 * 8]);
#pragma unroll
      for (int jd = 0; jd < 8; jd++) {
        const int s = ks * 8 + jd;
        bf16x8 vf = vr[s & 3];
        if (s + 4 < 32) {
          const int sn = s + 4, ksn = sn >> 3, jdn = sn & 7;
          vr[sn & 3] = *(const bf16x8*)(Vc + (jdn * 4 + ksn) * 512);
        }
        O[0][jd] = __builtin_amdgcn_mfma_f32_16x16x32_bf16(pf0, vf, O[0][jd], 0, 0, 0);
        O[1][jd] = __builtin_amdgcn_mfma_f32_16x16x32_bf16(pf1, vf, O[1][jd], 0, 0, 0);
      }
    }
  }
  // ---- finalize: reduce l across the 16-lane row groups, divide, store ----
#pragma unroll
  for (int d = 1; d < 16; d <<= 1)
#pragma unroll
    for (int i = 0; i < 2; i++)
#pragma unroll
      for (int r = 0; r < 4; r++)
        l_i[i][r] += __shfl_xor(l_i[i][r], d, 64);
#pragma unroll
  for (int i = 0; i < 2; i++)
#pragma unroll
    for (int r = 0; r < 4; r++) {
      float inv = 1.0f / l_i[i][r];
      long row = (long)(b * T_ + t0 + 32 * wave + 16 * i + q4 * 4 + r);
#pragma unroll
      for (int jd = 0; jd < 8; jd++)
        y[row * 2048 + h * HD + 16 * jd + l16] = f2bf(O[i][jd][r] * inv);
    }
}

// ---------------- launcher ----------------
extern "C" void kernel_launch(void* const* d_in, const int* in_sizes, int n_in,
                              void* d_out, int out_size, void* d_ws, size_t ws_size,
                              hipStream_t stream) {
  const float* x    = (const float*)d_in[0];
  const float* wq   = (const float*)d_in[1];
  const float* wk   = (const float*)d_in[2];
  const float* wv   = (const float*)d_in[3];
  const float* wo   = (const float*)d_in[4];
  const float* rope = (const float*)d_in[5];
  float* out = (float*)d_out;

  u16* xb   = (u16*)d_ws;                       // 8192*2048
  u16* wqkv = xb + (long)8192 * 2048;           // 3072*2048
  u16* wob  = wqkv + (long)3072 * 2048;         // 2048*2048
  u16* qkv  = wob + (long)2048 * 2048;          // 8192*3072
  u16* V2   = qkv + (long)8192 * 3072;          // 4.19M el
  u16* K2   = wqkv;                             // alias: wqkv dead after gemm1
  u16* yb   = xb;                               // reuse

  // one fused convert pass: 27262976 elements = 26624 blocks * 1024 el
  cvt_all<<<dim3(26624), dim3(256), 0, stream>>>(x, wq, wk, wv, wo, xb, wqkv, wob);

  // GEMM1 with fused RoPE epilogue: qkv = x @ wqkv^T; rope+scale on Q/K cols
  gemm256<1, 1><<<dim3(3072 / 256, 8192 / 256), dim3(512), 0, stream>>>(
      xb, wqkv, (void*)qkv, rope, 8192, 3072, 2048);

  krearr<<<dim3(2048), dim3(256), 0, stream>>>(qkv, K2);
  vrearr2<<<dim3(256), dim3(256), 0, stream>>>(qkv, V2);

  attn_kernel<<<dim3(T_ / 128, NH, B_), dim3(256), 0, stream>>>(qkv, K2, V2, yb);

  gemm256<0, 0><<<dim3(2048 / 256, 8192 / 256), dim3(512), 0, stream>>>(
      yb, wob, (void*)out, (const float*)nullptr, 8192, 2048, 2048);
}

// Round 8
// 393.832 us; speedup vs baseline: 1.4227x; 1.4227x over previous
//
#include <hip/hip_runtime.h>
#include <stdint.h>

typedef unsigned short u16;
typedef __attribute__((ext_vector_type(8))) short bf16x8;      // 8 bf16 = 4 VGPRs
typedef __attribute__((ext_vector_type(8))) unsigned short u16x8;
typedef __attribute__((ext_vector_type(4))) float f32x4;

#define B_  2
#define T_  4096
#define C_  2048
#define NH  16
#define NKV 4
#define HD  128

__device__ __forceinline__ u16 f2bf(float f) {
  union { float f; uint32_t u; } v; v.f = f;
  uint32_t u = v.u;
  u += 0x7fffu + ((u >> 16) & 1u);   // RNE
  return (u16)(u >> 16);
}
__device__ __forceinline__ float bf2f(u16 h) {
  union { uint32_t u; float f; } v; v.u = ((uint32_t)h) << 16;
  return v.f;
}

__device__ __forceinline__ void gload_lds16(const u16* g, u16* l) {
  __builtin_amdgcn_global_load_lds(
      (const __attribute__((address_space(1))) void*)g,
      (__attribute__((address_space(3))) void*)l, 16, 0, 0);
}

// ---------------- fused f32 -> bf16 convert (x, wq, wk, wv, wo in one grid) ----------------
__global__ void cvt_all(const float* __restrict__ x, const float* __restrict__ wq,
                        const float* __restrict__ wk, const float* __restrict__ wv,
                        const float* __restrict__ wo, u16* __restrict__ xb,
                        u16* __restrict__ wqkv, u16* __restrict__ wob) {
  long i = ((long)blockIdx.x * 256 + threadIdx.x) * 4;
  const float* src; u16* dst; long off;
  if (i < 16777216L)      { src = x;  dst = xb;              off = i; }
  else if (i < 20971520L) { src = wq; dst = wqkv;            off = i - 16777216L; }
  else if (i < 22020096L) { src = wk; dst = wqkv + 4194304L; off = i - 20971520L; }
  else if (i < 23068672L) { src = wv; dst = wqkv + 5242880L; off = i - 22020096L; }
  else                    { src = wo; dst = wob;             off = i - 23068672L; }
  float4 v = *(const float4*)(src + off);
  ushort4 o4;
  o4.x = f2bf(v.x); o4.y = f2bf(v.y); o4.z = f2bf(v.z); o4.w = f2bf(v.w);
  *(ushort4*)(dst + off) = o4;
}

// ---------------- K rearrange: frag-linear layout ----------------
// K2[bk][kb=key/16][ks=d/32][q4][l16=key%16][e=d%8]
__global__ void krearr(const u16* __restrict__ qkv, u16* __restrict__ K2) {
  int gid = blockIdx.x * 256 + threadIdx.x;
  int r = gid & 65535, bk = gid >> 16;
  int l16 = r & 15, q4 = (r >> 4) & 3, ks = (r >> 6) & 3, kb = r >> 8;
  int bb = bk >> 2, kv = bk & 3;
  const u16* src = qkv + ((long)(bb * T_ + kb * 16 + l16)) * 3072 + 2048 + kv * HD +
                   ks * 32 + q4 * 8;
  *(u16x8*)(K2 + (long)bk * 524288 + (long)r * 8) = *(const u16x8*)src;
}

// ---------------- V rearrange via LDS transpose (coalesced both sides) ----------------
// V2[bk][kc=key/128][jd=d/16][ks=(key%128)/32][q4][l16=d%16][e=key%8]
__global__ __launch_bounds__(256) void vrearr2(const u16* __restrict__ qkv,
                                               u16* __restrict__ V2) {
  const int bid = blockIdx.x;          // 0..255
  const int bk = bid >> 5, kc = bid & 31;
  const int bb = bk >> 2, kv = bk & 3;
  const int t = threadIdx.x;
  __shared__ u16 L[128 * 136];         // [key][d], pad 8 u16 (16B-aligned rows)
  {
    int key = t >> 1;
    int dh = (t & 1) * 64;
    const u16* src = qkv + ((long)(bb * T_ + kc * 128 + key)) * 3072 + 2560 + kv * HD + dh;
    u16* dst = L + key * 136 + dh;
#pragma unroll
    for (int u = 0; u < 8; u++)
      *(u16x8*)(dst + u * 8) = *(const u16x8*)(src + u * 8);
  }
  __syncthreads();
  u16* out = V2 + (long)bk * 524288 + (long)kc * 16384;
#pragma unroll
  for (int step = 0; step < 8; step++) {
    int o = step * 256 + t;            // 0..2047
    int l16 = o & 15, q4 = (o >> 4) & 3, ks = (o >> 6) & 3, jd = (o >> 8) & 7;
    int keyb = ks * 32 + q4 * 8;
    int d = jd * 16 + l16;
    u16x8 v;
#pragma unroll
    for (int e = 0; e < 8; e++) v[e] = L[(keyb + e) * 136 + d];
    *(u16x8*)(out + (long)o * 8) = v;
  }
}

// ---------------- bf16 GEMM: C[M][N] = A[M][K] * B[N][K]^T ----------------
// 256x256 tile, BK=64, 8 waves (2M x 4N), double-buffered 128 KiB LDS.
// READ-AHEAD pipeline, 2 barriers per K-tile (R2 structure, proven 121.6 us).
// Fused RoPE epilogue via LDS rope table.
#define GBAR() __builtin_amdgcn_s_barrier()
#define LGKM0() do { asm volatile("s_waitcnt lgkmcnt(0)" ::: "memory"); \
                     __builtin_amdgcn_sched_barrier(0); } while (0)

template <int WRITE_BF16, int ROPE>
__global__ __launch_bounds__(512, 2) void gemm256(const u16* __restrict__ A,
                                                  const u16* __restrict__ Bw,
                                                  void* __restrict__ Cv,
                                                  const float* __restrict__ rope,
                                                  int M, int N, int K) {
  __shared__ __align__(16) u16 lds[65536];   // 128 KiB
  const int tid = threadIdx.x;
  const int lane = tid & 63;
  const int wave = tid >> 6;
  const int q4 = lane >> 4, l16 = lane & 15;
  const int wm = wave >> 2, wn = wave & 3;

  // bijective XCD swizzle (launcher guarantees nwg % 8 == 0)
  const int nwg = gridDim.x * gridDim.y;
  const int orig = blockIdx.y * gridDim.x + blockIdx.x;
  const int swz = (orig & 7) * (nwg >> 3) + (orig >> 3);
  const int bm = swz / gridDim.x, bn = swz % gridDim.x;
  const long m0 = (long)bm * 256, n0 = (long)bn * 256;

  // ---- staging addressing: thread t -> LDS linear t*16 bytes (+8192) ----
  const int srow = tid >> 2;            // 0..127  (second load: +128)
  const int slot = tid & 3;
  const int sx = (slot ^ ((srow >> 1) & 3)) * 8;   // (srow+128) gives same XOR
  const u16* Ag0 = A + (m0 + srow) * K + sx;
  const u16* Ag1 = A + (m0 + srow + 128) * K + sx;
  const u16* Bg0 = Bw + (n0 + srow) * K + sx;
  const u16* Bg1 = Bw + (n0 + srow + 128) * K + sx;
  u16* ldst = lds + tid * 8;            // u16 units

  const int nkt = K >> 6;

#define STAGE_A(bufi, kh, kt)                                  \
  do {                                                         \
    long ko = ((long)(kt) << 6) + ((kh) << 5);                 \
    u16* d = ldst + (bufi) * 32768 + (kh) * 8192;              \
    gload_lds16(Ag0 + ko, d);                                  \
    gload_lds16(Ag1 + ko, d + 4096);                           \
  } while (0)
#define STAGE_B(bufi, kh, kt)                                  \
  do {                                                         \
    long ko = ((long)(kt) << 6) + ((kh) << 5);                 \
    u16* d = ldst + (bufi) * 32768 + 16384 + (kh) * 8192;      \
    gload_lds16(Bg0 + ko, d);                                  \
    gload_lds16(Bg1 + ko, d + 4096);                           \
  } while (0)

  // fragment LDS offsets (u16 units) for kh=0; kh=1 adds 8192.
  int offA[8], offB[4];
#pragma unroll
  for (int m = 0; m < 8; m++) {
    int r = wm * 128 + m * 16 + l16;
    offA[m] = r * 32 + ((q4 ^ ((r >> 1) & 3)) << 3);
  }
#pragma unroll
  for (int n = 0; n < 4; n++) {
    int r = wn * 64 + n * 16 + l16;
    offB[n] = 16384 + r * 32 + ((q4 ^ ((r >> 1) & 3)) << 3);
  }

  f32x4 acc[8][4] = {};

  // ---- prologue: tile0 (4 half-stages) + tile1 k0 (2 half-stages) ----
  STAGE_A(0, 0, 0); STAGE_B(0, 0, 0); STAGE_A(0, 1, 0); STAGE_B(0, 1, 0);
  if (nkt > 1) {
    STAGE_A(1, 0, 1); STAGE_B(1, 0, 1);
    asm volatile("s_waitcnt vmcnt(4)" ::: "memory");
  } else {
    asm volatile("s_waitcnt vmcnt(0)" ::: "memory");
  }
  GBAR();

  bf16x8 afX[4], afY[4], bvA[4], bvB[4];
  for (int kt = 0; kt < nkt; kt++) {
    const int bo = (kt & 1) * 32768;    // current read buffer offset (u16)
    // ---- P1: R1 (cold) ; stage A-k1 ; wait ; R2 under MFMA ----
#pragma unroll
    for (int m = 0; m < 4; m++) afX[m] = *(const bf16x8*)(lds + bo + offA[m]);
#pragma unroll
    for (int n = 0; n < 4; n++) bvA[n] = *(const bf16x8*)(lds + bo + offB[n]);
    if (kt + 1 < nkt) STAGE_A((kt + 1) & 1, 1, kt + 1);
    LGKM0();
#pragma unroll
    for (int m = 0; m < 4; m++) afY[m] = *(const bf16x8*)(lds + bo + offA[4 + m]);
    __builtin_amdgcn_s_setprio(1);
#pragma unroll
    for (int m = 0; m < 4; m++)
#pragma unroll
      for (int n = 0; n < 4; n++)
        acc[m][n] = __builtin_amdgcn_mfma_f32_16x16x32_bf16(afX[m], bvA[n], acc[m][n], 0, 0, 0);
    __builtin_amdgcn_s_setprio(0);
    // ---- P2: stage B-k1 ; wait R2 ; R3 under MFMA ; mid-BAR ----
    if (kt + 1 < nkt) STAGE_B((kt + 1) & 1, 1, kt + 1);
    LGKM0();
#pragma unroll
    for (int m = 0; m < 4; m++) afX[m] = *(const bf16x8*)(lds + bo + 8192 + offA[m]);
#pragma unroll
    for (int n = 0; n < 4; n++) bvB[n] = *(const bf16x8*)(lds + bo + 8192 + offB[n]);
    __builtin_amdgcn_s_setprio(1);
#pragma unroll
    for (int m = 0; m < 4; m++)
#pragma unroll
      for (int n = 0; n < 4; n++)
        acc[4 + m][n] = __builtin_amdgcn_mfma_f32_16x16x32_bf16(afY[m], bvA[n], acc[4 + m][n], 0, 0, 0);
    __builtin_amdgcn_s_setprio(0);
    GBAR();                              // k0 globally consumed -> reusable
    // ---- P3: stage A-k0(kt+2) into cur ; wait R3 ; R4 under MFMA ----
    if (kt + 2 < nkt) STAGE_A(kt & 1, 0, kt + 2);
    LGKM0();
#pragma unroll
    for (int m = 0; m < 4; m++) afY[m] = *(const bf16x8*)(lds + bo + 8192 + offA[4 + m]);
    __builtin_amdgcn_s_setprio(1);
#pragma unroll
    for (int m = 0; m < 4; m++)
#pragma unroll
      for (int n = 0; n < 4; n++)
        acc[m][n] = __builtin_amdgcn_mfma_f32_16x16x32_bf16(afX[m], bvB[n], acc[m][n], 0, 0, 0);
    __builtin_amdgcn_s_setprio(0);
    // ---- P4: stage B-k0(kt+2) ; wait R4 ; MFMA ; counted vmcnt ; BAR ----
    if (kt + 2 < nkt) STAGE_B(kt & 1, 0, kt + 2);
    LGKM0();
    __builtin_amdgcn_s_setprio(1);
#pragma unroll
    for (int m = 0; m < 4; m++)
#pragma unroll
      for (int n = 0; n < 4; n++)
        acc[4 + m][n] = __builtin_amdgcn_mfma_f32_16x16x32_bf16(afY[m], bvB[n], acc[4 + m][n], 0, 0, 0);
    __builtin_amdgcn_s_setprio(0);
    if (kt + 2 < nkt)
      asm volatile("s_waitcnt vmcnt(4)" ::: "memory");
    else
      asm volatile("s_waitcnt vmcnt(0)" ::: "memory");
    GBAR();
  }
#undef STAGE_A
#undef STAGE_B

  // ---- ROPE: stage this block's rope rows into (now dead) LDS ----
  if (ROPE) {
    float* rl = (float*)lds;
    const int rrow = tid >> 1;                 // 0..255
    const int rh = (tid & 1) * 64;             // col half
    const int rx = ((rrow >> 2) & 3) << 3;
    const float* rsrc = rope + ((long)((int)((m0 + rrow)) & (T_ - 1)) * 128 + rh);
    float* rdst = rl + rrow * 128;
#pragma unroll
    for (int v = 0; v < 16; v++) {
      int col = rh + v * 4;
      *(float4*)(rdst + (col ^ rx)) = *(const float4*)(rsrc + v * 4);
    }
    GBAR();
  }

  // ---- epilogue: C write, fused RoPE (C/D frag: row=q4*4+r, col=l16) ----
  const long crow0 = m0 + wm * 128;
  const long ccol0 = n0 + wn * 64;
  const float* rl = (const float*)lds;
#pragma unroll
  for (int m = 0; m < 8; m++)
#pragma unroll
    for (int n = 0; n < 4; n++) {
      const int cfrag = (int)(ccol0 + n * 16);
#pragma unroll
      for (int r = 0; r < 4; r++) {
        long row = crow0 + m * 16 + q4 * 4 + r;
        float x = acc[m][n][r];
        if (ROPE && cfrag < 2560) {
          int row_local = wm * 128 + m * 16 + q4 * 4 + r;      // (row_local>>2)&3 == q4
          int cc = ((cfrag & 127) + l16) ^ (q4 << 3);
          float2 cs = *(const float2*)(rl + row_local * 128 + (cc & ~1));  // (cos,sin)
          float px = __shfl_xor(x, 1, 64);
          // even (x=x0, px=x1): x0*cos - x1*sin ; odd (x=x1, px=x0): x0*sin + x1*cos
          float rot = ((l16 & 1) == 0) ? (x * cs.x - px * cs.y)
                                       : (px * cs.y + x * cs.x);
          if (cfrag < 2048) rot *= 0.1275174315f;  // q: 1/sqrt(D) * log2(e)
          x = rot;
        }
        if (WRITE_BF16)
          ((u16*)Cv)[row * (long)N + ccol0 + n * 16 + l16] = f2bf(x);
        else
          ((float*)Cv)[row * (long)N + ccol0 + n * 16 + l16] = x;
      }
    }
}

// ---------------- sliding-window attention ----------------
// R8 changes vs R7 (post-mortem: launch_bounds(256,4) capped VGPR at 64 ->
// 700 MB/dispatch scratch spill = the whole 209 us):
//  1. __launch_bounds__(256,2): no VGPR cap pressure (state ~180 regs).
//  2. V chunk (32 KB) staged to LDS via async global_load_lds issued at chunk
//     start; latency hides under the QK phase. PV reads V from LDS with a
//     4-deep ds ring (LDS latency ~120cy vs ~4-step slack). Removes the PV
//     per-step global-latency exposure (the dominant stall).
//  3. Keep XCD-chunked swizzle (one (b,kvh) K/V pair per XCD -> L2-pinned)
//     and K 2-j-deep register ring.
// LDS: Pl 34 KB + Vl 32 KB = 66.6 KB -> 2 blocks/CU, 8 waves/CU.
__global__ __launch_bounds__(256, 2) void attn_kernel(const u16* __restrict__ qkv,
                                                      const u16* __restrict__ K2,
                                                      const u16* __restrict__ V2,
                                                      u16* __restrict__ y) {
  const int lin = blockIdx.x + (int)gridDim.x * (blockIdx.y + (int)gridDim.y * blockIdx.z);
  const int swz = (lin & 7) * 128 + (lin >> 3);   // bijective: 1024 = 8*128
  const int tc = swz & 31, h = (swz >> 5) & 15, b = swz >> 9;
  const int t0 = tc * 128;
  const int kvh = h >> 2;
  __shared__ u16 Pl[4 * 32 * 136];
  __shared__ __align__(16) u16 Vl[16384];          // 32 KB staged V chunk
  const int tid = threadIdx.x, wave = tid >> 6, lane = tid & 63;
  const int q4 = lane >> 4, l16 = lane & 15;
  u16* Pw = Pl + wave * (32 * 136);

  bf16x8 qf[2][4];
#pragma unroll
  for (int i = 0; i < 2; i++)
#pragma unroll
    for (int ks = 0; ks < 4; ks++)
      qf[i][ks] = *(const bf16x8*)(qkv +
          ((long)(b * T_ + t0 + 32 * wave + 16 * i + l16)) * 3072 + h * HD + ks * 32 + q4 * 8);

  f32x4 O[2][8] = {};
  float l_i[2][4] = {};

  const u16* Kb = K2 + (long)(b * NKV + kvh) * 524288 + lane * 8;
  const u16* Vb = V2 + (long)(b * NKV + kvh) * 524288;   // no lane offset (staging)

  int kstart = t0 - 256; if (kstart < 0) kstart = 0;
  for (int k0 = kstart; k0 <= t0; k0 += 128) {
    const u16* Kc = Kb + (long)(k0 >> 4) * 2048;     // kb0*4*512
    const u16* Vc = Vb + (long)(k0 >> 7) * 16384;    // kc*8*4*512
    // ---- issue async V stage (32 KB, 8 x gload_lds per thread) ----
#pragma unroll
    for (int i = 0; i < 8; i++)
      gload_lds16(Vc + i * 2048 + tid * 8, Vl + i * 2048 + tid * 8);
    const int dbase0 = t0 + 32 * wave + q4 * 4 - k0 - l16;
    // ---- S = Q K^T; K frags 2-j-deep ring; P -> wave-private LDS ----
    bf16x8 kr[2][4];
#pragma unroll
    for (int ks = 0; ks < 4; ks++) kr[0][ks] = *(const bf16x8*)(Kc + ks * 512);
#pragma unroll
    for (int ks = 0; ks < 4; ks++) kr[1][ks] = *(const bf16x8*)(Kc + 2048 + ks * 512);
#pragma unroll
    for (int j = 0; j < 8; j++) {
      bf16x8 kf[4];
#pragma unroll
      for (int ks = 0; ks < 4; ks++) kf[ks] = kr[j & 1][ks];
      if (j + 2 < 8)
#pragma unroll
        for (int ks = 0; ks < 4; ks++)
          kr[j & 1][ks] = *(const bf16x8*)(Kc + (j + 2) * 2048 + ks * 512);
      f32x4 s0 = {}, s1 = {};
#pragma unroll
      for (int ks = 0; ks < 4; ks++) {
        s0 = __builtin_amdgcn_mfma_f32_16x16x32_bf16(qf[0][ks], kf[ks], s0, 0, 0, 0);
        s1 = __builtin_amdgcn_mfma_f32_16x16x32_bf16(qf[1][ks], kf[ks], s1, 0, 0, 0);
      }
#pragma unroll
      for (int r = 0; r < 4; r++) {
        int d0 = dbase0 + r - 16 * j;               // q - k for i=0
        float p0 = __builtin_amdgcn_exp2f(s0[r]);
        p0 = ((unsigned)d0 <= 255u) ? p0 : 0.f;     // band mask, all chunks
        l_i[0][r] += p0;
        Pw[(q4 * 4 + r) * 136 + 16 * j + l16] = f2bf(p0);
        int d1 = d0 + 16;                            // i=1
        float p1 = __builtin_amdgcn_exp2f(s1[r]);
        p1 = ((unsigned)d1 <= 255u) ? p1 : 0.f;
        l_i[1][r] += p1;
        Pw[(16 + q4 * 4 + r) * 136 + 16 * j + l16] = f2bf(p1);
      }
    }
    // ---- V staged + visible to all waves ----
    asm volatile("s_waitcnt vmcnt(0)" ::: "memory");
    GBAR();
    // ---- O += P V ; V frags from LDS, 4-deep ds ring ----
    // step s = ks*8+jd consumes frag (jd*4+ks); preload s=0..3 -> frags 0,4,8,12
    bf16x8 vr[4];
#pragma unroll
    for (int p = 0; p < 4; p++)
      vr[p] = *(const bf16x8*)(Vl + (p * 4) * 512 + lane * 8);
#pragma unroll
    for (int ks = 0; ks < 4; ks++) {
      bf16x8 pf0 = *(const bf16x8*)(&Pw[l16 * 136 + ks * 32 + q4 * 8]);
      bf16x8 pf1 = *(const bf16x8*)(&Pw[(16 + l16) * 136 + ks * 32 + q4 * 8]);
#pragma unroll
      for (int jd = 0; jd < 8; jd++) {
        const int s = ks * 8 + jd;
        bf16x8 vf = vr[s & 3];
        if (s + 4 < 32) {
          const int sn = s + 4, ksn = sn >> 3, jdn = sn & 7;
          vr[sn & 3] = *(const bf16x8*)(Vl + (jdn * 4 + ksn) * 512 + lane * 8);
        }
        O[0][jd] = __builtin_amdgcn_mfma_f32_16x16x32_bf16(pf0, vf, O[0][jd], 0, 0, 0);
        O[1][jd] = __builtin_amdgcn_mfma_f32_16x16x32_bf16(pf1, vf, O[1][jd], 0, 0, 0);
      }
    }
    GBAR();   // all waves done reading Vl -> next chunk may restage
  }
  // ---- finalize: reduce l across the 16-lane row groups, divide, store ----
#pragma unroll
  for (int d = 1; d < 16; d <<= 1)
#pragma unroll
    for (int i = 0; i < 2; i++)
#pragma unroll
      for (int r = 0; r < 4; r++)
        l_i[i][r] += __shfl_xor(l_i[i][r], d, 64);
#pragma unroll
  for (int i = 0; i < 2; i++)
#pragma unroll
    for (int r = 0; r < 4; r++) {
      float inv = 1.0f / l_i[i][r];
      long row = (long)(b * T_ + t0 + 32 * wave + 16 * i + q4 * 4 + r);
#pragma unroll
      for (int jd = 0; jd < 8; jd++)
        y[row * 2048 + h * HD + 16 * jd + l16] = f2bf(O[i][jd][r] * inv);
    }
}

// ---------------- launcher ----------------
extern "C" void kernel_launch(void* const* d_in, const int* in_sizes, int n_in,
                              void* d_out, int out_size, void* d_ws, size_t ws_size,
                              hipStream_t stream) {
  const float* x    = (const float*)d_in[0];
  const float* wq   = (const float*)d_in[1];
  const float* wk   = (const float*)d_in[2];
  const float* wv   = (const float*)d_in[3];
  const float* wo   = (const float*)d_in[4];
  const float* rope = (const float*)d_in[5];
  float* out = (float*)d_out;

  u16* xb   = (u16*)d_ws;                       // 8192*2048
  u16* wqkv = xb + (long)8192 * 2048;           // 3072*2048
  u16* wob  = wqkv + (long)3072 * 2048;         // 2048*2048
  u16* qkv  = wob + (long)2048 * 2048;          // 8192*3072
  u16* V2   = qkv + (long)8192 * 3072;          // 4.19M el
  u16* K2   = wqkv;                             // alias: wqkv dead after gemm1
  u16* yb   = xb;                               // reuse

  // one fused convert pass: 27262976 elements = 26624 blocks * 1024 el
  cvt_all<<<dim3(26624), dim3(256), 0, stream>>>(x, wq, wk, wv, wo, xb, wqkv, wob);

  // GEMM1 with fused RoPE epilogue: qkv = x @ wqkv^T; rope+scale on Q/K cols
  gemm256<1, 1><<<dim3(3072 / 256, 8192 / 256), dim3(512), 0, stream>>>(
      xb, wqkv, (void*)qkv, rope, 8192, 3072, 2048);

  krearr<<<dim3(2048), dim3(256), 0, stream>>>(qkv, K2);
  vrearr2<<<dim3(256), dim3(256), 0, stream>>>(qkv, V2);

  attn_kernel<<<dim3(T_ / 128, NH, B_), dim3(256), 0, stream>>>(qkv, K2, V2, yb);

  gemm256<0, 0><<<dim3(2048 / 256, 8192 / 256), dim3(512), 0, stream>>>(
      yb, wob, (void*)out, (const float*)nullptr, 8192, 2048, 2048);
}